// Round 10
// baseline (219.504 us; speedup 1.0000x reference)
//
#include <hip/hip_runtime.h>
#include <hip/hip_bf16.h>

constexpr int LAYERS = 24;
constexpr int DIM    = 2048;
constexpr int NBLK   = 8;
constexpr float EPSV = 1e-6f;
constexpr int TPB    = 1024;
constexpr int EPT    = 2;            // one float2 slice per thread
constexpr int NGRP   = TPB / 16;     // 64 16-lane reduction groups
constexpr int NSLOT  = 147;          // total block-wide reduced scalars
constexpr int RSTR   = NSLOT + 2;    // odd stride

typedef float vf2 __attribute__((ext_vector_type(2)));

// Reduced-value layout (slot indices):
//   slot 0: ssq(emb)
//   layer l (1..23), m=l/3, i=l%3, off=OFF_TAB[l]:
//     off+0        : dot(emb, qw_l)
//     off+1+s      : dot(S_s, qw_l)          s = 0..m-1
//     i>0:  off+m+1: dot(part_l, qw_l),  off+m+2: ssq(part_l)
//     i==0: off+m+1: ssq(S_{m-1})  (computed from f32 part before overwrite)
__device__ constexpr int OFF_TAB[24] =
    {0,1,4,7,10,14,18,22,27,32,37,43,49,55,62,69,76,84,92,100,109,118,127,137};
__device__ constexpr int SSQS[7] = {9,21,36,54,75,99,126};  // ssq(S_s) slots

__device__ __forceinline__ unsigned pk2(float a, float b) {
    __hip_bfloat162 h2(__float2bfloat16(a), __float2bfloat16(b));
    union { __hip_bfloat162 h; unsigned u; } c; c.h = h2; return c.u;
}
__device__ __forceinline__ float upk(unsigned p, int hi) {
    union { unsigned u; float f; } c;
    c.u = hi ? (p & 0xffff0000u) : (p << 16);
    return c.f;
}

// DPP tree-sum over each 16-lane group (pure VALU, no DS pipe).
template<int CTRL>
__device__ __forceinline__ float dpp_add(float x) {
    int y = __builtin_amdgcn_update_dpp(0, __float_as_int(x), CTRL, 0xF, 0xF, true);
    return x + __int_as_float(y);
}
__device__ __forceinline__ float grp16_sum(float x) {
    x = dpp_add<0xB1>(x);    // + lane^1   (quad_perm[1,0,3,2])
    x = dpp_add<0x4E>(x);    // + lane^2   (quad_perm[2,3,0,1])
    x = dpp_add<0x141>(x);   // row_half_mirror
    x = dpp_add<0x140>(x);   // row_mirror
    return x;                // all 16 lanes hold the group sum
}

__global__ void prep_qw_kernel(const float* __restrict__ q,
                               const float* __restrict__ w,
                               float* __restrict__ qw, int n) {
    int idx = blockIdx.x * blockDim.x + threadIdx.x;
    if (idx < n) qw[idx] = q[idx] * w[idx & (DIM - 1)];
}

template<bool PREMUL>
__global__ void __launch_bounds__(TPB, 6)   // cap ~85 regs; demand ~70 -> 6 waves/SIMD
block_attn_res_kernel(const float* __restrict__ lo,   // (L, B*T, D)
                      const float* __restrict__ emb,  // (B*T, D)
                      const float* __restrict__ q1,   // premultiplied q*w (L,D) or raw q
                      const float* __restrict__ wgt,  // (D) -- only if !PREMUL
                      float* __restrict__ out,        // (L, B*T, D)
                      int bt_total)
{
    const int bt   = blockIdx.x;
    const int tid  = threadIdx.x;
    const int lane = tid & 63;
    const int grp  = tid >> 4;                   // 16-lane group id, 0..63
    const int c0   = tid * 2;                    // thread owns d-indices [2t,2t+2)

    __shared__ float red[NGRP][RSTR];      // group partials
    __shared__ float redJ[NSLOT + 1];      // joined scalars
    __shared__ float ab[LAYERS][12];       // normalized alphas per layer

    const float invD = 1.f / (float)DIM;
    const size_t lstride = (size_t)bt_total * DIM;
    const float* lop = lo + (size_t)bt * DIM + c0;

    // 16-lane DPP tree sum; group leader writes LDS
    auto wred = [&](float x, int slot) {
        x = grp16_sum(x);
        if ((lane & 15) == 0) red[grp][slot] = x;
    };

    // weight slice (only needed when !PREMUL)
    float wv[EPT];
    if (!PREMUL) {
        vf2 w0 = *reinterpret_cast<const vf2*>(wgt + c0);
        wv[0]=w0.x; wv[1]=w0.y;
    }

    // ---- embedding slice
    float e[EPT];
    {
        vf2 v0 = __builtin_nontemporal_load(
            reinterpret_cast<const vf2*>(emb + (size_t)bt * DIM + c0));
        e[0]=v0.x; e[1]=v0.y;
    }

    unsigned fpk[LAYERS-1];   // f_0..f_22 packed bf16x2 (23 regs)
    unsigned Spk[NBLK-1];     // finished block sums S_0..S_6, bf16x2
    float part[EPT];          // running within-block partial (f32)

    // ========== PHASE 1: stream, evolve, emit reduction partials ==========
    // l = 0: out = emb (single-source softmax), seed part with f_0
    {
        vf2 u0 = __builtin_nontemporal_load(reinterpret_cast<const vf2*>(lop));
        part[0]=u0.x; part[1]=u0.y;
        fpk[0] = pk2(part[0], part[1]);

        vf2 w0; w0.x=e[0]; w0.y=e[1];
        *reinterpret_cast<vf2*>(out + (size_t)bt * DIM + c0) = w0;

        float sq = e[0]*e[0] + e[1]*e[1];
        wred(sq, 0);
    }

    // ---- 4-deep f prefetch (HBM), 2-deep qw prefetch (L2-resident)
    float fb[4][EPT], qb[2][EPT];
    {
        vf2 u;
        u = __builtin_nontemporal_load(reinterpret_cast<const vf2*>(lop + 1 * lstride));
        fb[1][0]=u.x; fb[1][1]=u.y;
        u = __builtin_nontemporal_load(reinterpret_cast<const vf2*>(lop + 2 * lstride));
        fb[2][0]=u.x; fb[2][1]=u.y;
        u = __builtin_nontemporal_load(reinterpret_cast<const vf2*>(lop + 3 * lstride));
        fb[3][0]=u.x; fb[3][1]=u.y;
        u = __builtin_nontemporal_load(reinterpret_cast<const vf2*>(lop + 4 * lstride));
        fb[0][0]=u.x; fb[0][1]=u.y;
        vf2 q;
        q = *reinterpret_cast<const vf2*>(q1 + (size_t)1 * DIM + c0);
        qb[1][0]=q.x; qb[1][1]=q.y;
        q = *reinterpret_cast<const vf2*>(q1 + (size_t)2 * DIM + c0);
        qb[0][0]=q.x; qb[0][1]=q.y;
    }

    #pragma unroll
    for (int l = 1; l < LAYERS; ++l) {
        const int m   = l / 3;
        const int i   = l - 3 * m;
        const int off = OFF_TAB[l];
        const int pf  = l & 3;
        const int pq  = l & 1;

        // copy out current buffers
        float qwv[EPT];
        #pragma unroll
        for (int j = 0; j < EPT; ++j)
            qwv[j] = PREMUL ? qb[pq][j] : qb[pq][j] * wv[j];
        float fC[EPT];
        if (l < LAYERS - 1) {
            #pragma unroll
            for (int j = 0; j < EPT; ++j) fC[j] = fb[pf][j];
        }

        // issue deep prefetches
        if (l + 4 <= LAYERS - 2) {
            vf2 u0 = __builtin_nontemporal_load(
                reinterpret_cast<const vf2*>(lop + (size_t)(l + 4) * lstride));
            fb[pf][0]=u0.x; fb[pf][1]=u0.y;
        }
        if (l + 2 <= LAYERS - 1) {
            vf2 v0 = *reinterpret_cast<const vf2*>(q1 + (size_t)(l + 2) * DIM + c0);
            qb[pq][0]=v0.x; qb[pq][1]=v0.y;
        }

        // dot(emb, qw)
        wred(e[0]*qwv[0] + e[1]*qwv[1], off);

        // dot(S_s, qw); at i==0 the newest S (s=m-1) is still in f32 `part`
        #pragma unroll
        for (int s = 0; s < NBLK - 1; ++s) {
            if (s < m) {
                float dv;
                if (s == m - 1 && i == 0) {
                    dv = part[0]*qwv[0] + part[1]*qwv[1];
                } else {
                    dv = upk(Spk[s],0)*qwv[0] + upk(Spk[s],1)*qwv[1];
                }
                wred(dv, off + 1 + s);
            }
        }
        if (i > 0) {
            wred(part[0]*qwv[0] + part[1]*qwv[1], off + m + 1);
            wred(part[0]*part[0] + part[1]*part[1], off + m + 2);
        } else {
            // part still holds S_{m-1} in f32 here
            wred(part[0]*part[0] + part[1]*part[1], off + m + 1);
        }

        // advance partial / finalize block sum
        if (l < LAYERS - 1) {
            if (i == 0) {
                part[0] = fC[0]; part[1] = fC[1];
            } else {
                part[0] += fC[0]; part[1] += fC[1];
            }
            fpk[l] = pk2(fC[0], fC[1]);
            if (i == 2 && m < NBLK - 1) {
                Spk[m] = pk2(part[0], part[1]);
            }
        }
    }

    __syncthreads();   // barrier 1: all group partials in red[][]

    // ========== PHASE 2a: join 64 group partials per slot (4-acc tree) ====
    if (tid < NSLOT) {
        float a0 = 0.f, a1 = 0.f, a2 = 0.f, a3 = 0.f;
        #pragma unroll
        for (int g = 0; g < NGRP; g += 4) {
            a0 += red[g + 0][tid];
            a1 += red[g + 1][tid];
            a2 += red[g + 2][tid];
            a3 += red[g + 3][tid];
        }
        redJ[tid] = (a0 + a1) + (a2 + a3);
    }
    __syncthreads();   // barrier 2: joined scalars ready

    // ========== PHASE 2b: per-layer scores + softmax (23 threads) ==========
    if (tid >= 1 && tid < LAYERS) {
        const int l = tid;
        const int m = l / 3;
        const int i = l - 3 * m;
        const int off = OFF_TAB[l];
        const float ssqe = redJ[0];
        float sce = redJ[off] * rsqrtf(ssqe * invD + EPSV);
        float mx = sce;
        float scS[NBLK - 1];
        #pragma unroll
        for (int s = 0; s < NBLK - 1; ++s) {
            if (s < m) {
                scS[s] = redJ[off + 1 + s] * rsqrtf(redJ[SSQS[s]] * invD + EPSV);
                mx = fmaxf(mx, scS[s]);
            }
        }
        float scp = 0.f;
        if (i > 0) {
            scp = redJ[off + m + 1] * rsqrtf(redJ[off + m + 2] * invD + EPSV);
            mx = fmaxf(mx, scp);
        }
        float ee = __expf(sce - mx), den = ee;
        float es[NBLK - 1];
        #pragma unroll
        for (int s = 0; s < NBLK - 1; ++s) {
            es[s] = (s < m) ? __expf(scS[s] - mx) : 0.f;
            den += es[s];
        }
        float ep = 0.f;
        if (i > 0) { ep = __expf(scp - mx); den += ep; }
        const float inv = 1.f / den;
        ab[l][0] = ee * inv;
        #pragma unroll
        for (int s = 0; s < NBLK - 1; ++s)
            if (s < m) ab[l][1 + s] = es[s] * inv;
        if (i > 0) ab[l][1 + m] = ep * inv;
    }
    __syncthreads();   // barrier 3: alphas ready

    // ========== PHASE 3: emit outputs (no sync, pure FMA) ==========
    part[0] = upk(fpk[0],0); part[1] = upk(fpk[0],1);

    #pragma unroll
    for (int l = 1; l < LAYERS; ++l) {
        const int m = l / 3;
        const int i = l - 3 * m;

        float h[EPT];
        {
            const float a0 = ab[l][0];
            h[0] = a0 * e[0]; h[1] = a0 * e[1];
        }
        #pragma unroll
        for (int s = 0; s < NBLK - 1; ++s) {
            if (s < m) {
                const float a = ab[l][1 + s];
                h[0] += a * upk(Spk[s],0);
                h[1] += a * upk(Spk[s],1);
            }
        }
        if (i > 0) {
            const float a = ab[l][1 + m];
            h[0] += a * part[0];
            h[1] += a * part[1];
        }

        {
            vf2 w0; w0.x=h[0]; w0.y=h[1];
            *reinterpret_cast<vf2*>(out + ((size_t)l * bt_total + bt) * DIM + c0) = w0;
        }

        if (l < LAYERS - 1) {
            if (i == 0) {
                part[0] = upk(fpk[l],0); part[1] = upk(fpk[l],1);
            } else {
                part[0] += upk(fpk[l],0); part[1] += upk(fpk[l],1);
            }
        }
    }
}

extern "C" void kernel_launch(void* const* d_in, const int* in_sizes, int n_in,
                              void* d_out, int out_size, void* d_ws, size_t ws_size,
                              hipStream_t stream) {
    const float* lo  = (const float*)d_in[0];  // layer_outputs (L,B,T,D)
    const float* emb = (const float*)d_in[1];  // embedding (B,T,D)
    const float* qry = (const float*)d_in[2];  // queries (L,D)
    const float* wgt = (const float*)d_in[3];  // key_norm_weight (D)
    float* outp = (float*)d_out;

    const int bt_total = in_sizes[1] / DIM;    // B*T
    const int nq = in_sizes[2];                // L*D

    if (ws_size >= (size_t)nq * sizeof(float)) {
        float* qwbuf = (float*)d_ws;
        prep_qw_kernel<<<(nq + 255) / 256, 256, 0, stream>>>(qry, wgt, qwbuf, nq);
        block_attn_res_kernel<true><<<bt_total, TPB, 0, stream>>>(
            lo, emb, qwbuf, nullptr, outp, bt_total);
    } else {
        block_attn_res_kernel<false><<<bt_total, TPB, 0, stream>>>(
            lo, emb, qry, wgt, outp, bt_total);
    }
}

// Round 11
// 195.602 us; speedup vs baseline: 1.1222x; 1.1222x over previous
//
#include <hip/hip_runtime.h>
#include <hip/hip_bf16.h>

constexpr int LAYERS = 24;
constexpr int DIM    = 2048;
constexpr int NBLK   = 8;
constexpr float EPSV = 1e-6f;
constexpr int TPB    = 512;
constexpr int EPT    = 4;            // one float4 slice per thread
constexpr int NSLOT  = 147;          // total block-wide reduced scalars
constexpr int RSTR   = NSLOT + 2;    // odd stride

typedef float vf4 __attribute__((ext_vector_type(4)));

// Reduced-value layout (slot indices):
//   slot 0: ssq(emb)
//   layer l (1..23), m=l/3, i=l%3, off=OFF_TAB[l]:
//     off+0        : dot(emb, qw_l)
//     off+1+s      : dot(S_s, qw_l)          s = 0..m-1
//     i>0:  off+m+1: dot(part_l, qw_l),  off+m+2: ssq(part_l)
//     i==0: off+m+1: ssq(S_{m-1})  (computed from f32 part before overwrite)
__device__ constexpr int OFF_TAB[24] =
    {0,1,4,7,10,14,18,22,27,32,37,43,49,55,62,69,76,84,92,100,109,118,127,137};
__device__ constexpr int SSQS[7] = {9,21,36,54,75,99,126};  // ssq(S_s) slots

__device__ __forceinline__ unsigned pk2(float a, float b) {
    __hip_bfloat162 h2(__float2bfloat16(a), __float2bfloat16(b));
    union { __hip_bfloat162 h; unsigned u; } c; c.h = h2; return c.u;
}
__device__ __forceinline__ float upk(unsigned p, int hi) {
    union { unsigned u; float f; } c;
    c.u = hi ? (p & 0xffff0000u) : (p << 16);
    return c.f;
}

// DPP tree-sum over each 16-lane group (pure VALU, no DS pipe).
template<int CTRL>
__device__ __forceinline__ float dpp_add(float x) {
    int y = __builtin_amdgcn_update_dpp(0, __float_as_int(x), CTRL, 0xF, 0xF, true);
    return x + __int_as_float(y);
}
__device__ __forceinline__ float grp16_sum(float x) {
    x = dpp_add<0xB1>(x);    // + lane^1   (quad_perm[1,0,3,2])
    x = dpp_add<0x4E>(x);    // + lane^2   (quad_perm[2,3,0,1])
    x = dpp_add<0x141>(x);   // row_half_mirror
    x = dpp_add<0x140>(x);   // row_mirror
    return x;                // all 16 lanes hold the group sum
}

__global__ void prep_qw_kernel(const float* __restrict__ q,
                               const float* __restrict__ w,
                               float* __restrict__ qw, int n) {
    int idx = blockIdx.x * blockDim.x + threadIdx.x;
    if (idx < n) qw[idx] = q[idx] * w[idx & (DIM - 1)];
}

template<bool PREMUL>
__global__ void __launch_bounds__(TPB, 4)   // cap 128 unified regs; demand ~116
block_attn_res_kernel(const float* __restrict__ lo,   // (L, B*T, D)
                      const float* __restrict__ emb,  // (B*T, D)
                      const float* __restrict__ q1,   // premultiplied q*w (L,D) or raw q
                      const float* __restrict__ wgt,  // (D) -- only if !PREMUL
                      float* __restrict__ out,        // (L, B*T, D)
                      int bt_total)
{
    const int bt   = blockIdx.x;
    const int tid  = threadIdx.x;
    const int lane = tid & 63;
    const int wid  = tid >> 6;
    const int grp  = (wid << 2) | (lane >> 4);   // 16-lane group id, 0..31
    const int c0   = tid * 4;                    // thread owns d-indices [4t,4t+4)

    __shared__ float red[32][RSTR];        // group partials
    __shared__ float redJ[NSLOT + 1];      // joined scalars
    __shared__ float ab[LAYERS][12];       // normalized alphas per layer

    const float invD = 1.f / (float)DIM;
    const size_t lstride = (size_t)bt_total * DIM;
    const float* lop = lo + (size_t)bt * DIM + c0;

    // 16-lane DPP tree sum; group leader writes LDS
    auto wred = [&](float x, int slot) {
        x = grp16_sum(x);
        if ((lane & 15) == 0) red[grp][slot] = x;
    };

    // weight slice (only needed when !PREMUL)
    float wv[EPT];
    if (!PREMUL) {
        vf4 w0 = *reinterpret_cast<const vf4*>(wgt + c0);
        wv[0]=w0.x; wv[1]=w0.y; wv[2]=w0.z; wv[3]=w0.w;
    }

    // ---- embedding slice
    float e[EPT];
    {
        vf4 v0 = __builtin_nontemporal_load(
            reinterpret_cast<const vf4*>(emb + (size_t)bt * DIM + c0));
        e[0]=v0.x; e[1]=v0.y; e[2]=v0.z; e[3]=v0.w;
    }

    unsigned pp[16][EPT/2];   // part snapshots at the 16 i>0 layers, bf16x2 (32 regs)
    unsigned Spk[NBLK-1][EPT/2];  // finished block sums S_0..S_6, bf16x2 (14 regs)
    float part[EPT];          // running within-block partial (f32)

    // ========== PHASE 1: stream, evolve, emit reduction partials ==========
    // l = 0: out = emb (single-source softmax), seed part with f_0
    {
        vf4 u0 = __builtin_nontemporal_load(reinterpret_cast<const vf4*>(lop));
        part[0]=u0.x; part[1]=u0.y; part[2]=u0.z; part[3]=u0.w;

        vf4 w0; w0.x=e[0]; w0.y=e[1]; w0.z=e[2]; w0.w=e[3];
        *reinterpret_cast<vf4*>(out + (size_t)bt * DIM + c0) = w0;

        float sq = e[0]*e[0] + e[1]*e[1] + e[2]*e[2] + e[3]*e[3];
        wred(sq, 0);
    }

    // ---- 8-deep f prefetch (HBM), 2-deep qw prefetch (L2-resident)
    float fb[8][EPT], qb[2][EPT];
    {
        #pragma unroll
        for (int k = 1; k <= 8; ++k) {
            vf4 u = __builtin_nontemporal_load(
                reinterpret_cast<const vf4*>(lop + (size_t)k * lstride));
            fb[k & 7][0]=u.x; fb[k & 7][1]=u.y; fb[k & 7][2]=u.z; fb[k & 7][3]=u.w;
        }
        vf4 q;
        q = *reinterpret_cast<const vf4*>(q1 + (size_t)1 * DIM + c0);
        qb[1][0]=q.x; qb[1][1]=q.y; qb[1][2]=q.z; qb[1][3]=q.w;
        q = *reinterpret_cast<const vf4*>(q1 + (size_t)2 * DIM + c0);
        qb[0][0]=q.x; qb[0][1]=q.y; qb[0][2]=q.z; qb[0][3]=q.w;
    }

    #pragma unroll
    for (int l = 1; l < LAYERS; ++l) {
        const int m   = l / 3;
        const int i   = l - 3 * m;
        const int off = OFF_TAB[l];
        const int pf  = l & 7;
        const int pq  = l & 1;

        // copy out current buffers
        float qwv[EPT];
        #pragma unroll
        for (int j = 0; j < EPT; ++j)
            qwv[j] = PREMUL ? qb[pq][j] : qb[pq][j] * wv[j];
        float fC[EPT];
        if (l < LAYERS - 1) {
            #pragma unroll
            for (int j = 0; j < EPT; ++j) fC[j] = fb[pf][j];
        }

        // issue deep prefetches (8 layers of cover for f)
        if (l + 8 <= LAYERS - 2) {
            vf4 u0 = __builtin_nontemporal_load(
                reinterpret_cast<const vf4*>(lop + (size_t)(l + 8) * lstride));
            fb[pf][0]=u0.x; fb[pf][1]=u0.y; fb[pf][2]=u0.z; fb[pf][3]=u0.w;
        }
        if (l + 2 <= LAYERS - 1) {
            vf4 v0 = *reinterpret_cast<const vf4*>(q1 + (size_t)(l + 2) * DIM + c0);
            qb[pq][0]=v0.x; qb[pq][1]=v0.y; qb[pq][2]=v0.z; qb[pq][3]=v0.w;
        }

        // dot(emb, qw)
        {
            float dv = e[0]*qwv[0] + e[1]*qwv[1] + e[2]*qwv[2] + e[3]*qwv[3];
            wred(dv, off);
        }
        // dot(S_s, qw); at i==0 the newest S (s=m-1) is still in f32 `part`
        #pragma unroll
        for (int s = 0; s < NBLK - 1; ++s) {
            if (s < m) {
                float dv;
                if (s == m - 1 && i == 0) {
                    dv = part[0]*qwv[0] + part[1]*qwv[1]
                       + part[2]*qwv[2] + part[3]*qwv[3];
                } else {
                    dv = upk(Spk[s][0],0)*qwv[0] + upk(Spk[s][0],1)*qwv[1]
                       + upk(Spk[s][1],0)*qwv[2] + upk(Spk[s][1],1)*qwv[3];
                }
                wred(dv, off + 1 + s);
            }
        }
        if (i > 0) {
            float dv = part[0]*qwv[0] + part[1]*qwv[1]
                     + part[2]*qwv[2] + part[3]*qwv[3];
            float sq = part[0]*part[0] + part[1]*part[1]
                     + part[2]*part[2] + part[3]*part[3];
            wred(dv, off + m + 1);
            wred(sq, off + m + 2);
            // snapshot part_l for phase 3 (bf16)
            const int si = 2 * m + (i - 1);
            pp[si][0] = pk2(part[0], part[1]);
            pp[si][1] = pk2(part[2], part[3]);
        } else {
            // part still holds S_{m-1} in f32 here
            float sq = part[0]*part[0] + part[1]*part[1]
                     + part[2]*part[2] + part[3]*part[3];
            wred(sq, off + m + 1);
        }

        // advance partial / finalize block sum
        if (l < LAYERS - 1) {
            if (i == 0) {
                #pragma unroll
                for (int j = 0; j < EPT; ++j) part[j] = fC[j];
            } else {
                #pragma unroll
                for (int j = 0; j < EPT; ++j) part[j] += fC[j];
            }
            if (i == 2 && m < NBLK - 1) {
                Spk[m][0] = pk2(part[0], part[1]);
                Spk[m][1] = pk2(part[2], part[3]);
            }
        }
    }

    __syncthreads();   // barrier 1: all group partials in red[][]

    // ========== PHASE 2a: join 32 group partials per slot ==========
    if (tid < NSLOT) {
        float s = 0.f;
        #pragma unroll
        for (int g = 0; g < 32; ++g) s += red[g][tid];
        redJ[tid] = s;
    }
    __syncthreads();   // barrier 2: joined scalars ready

    // ========== PHASE 2b: per-layer scores + softmax (23 threads) ==========
    if (tid >= 1 && tid < LAYERS) {
        const int l = tid;
        const int m = l / 3;
        const int i = l - 3 * m;
        const int off = OFF_TAB[l];
        const float ssqe = redJ[0];
        float sce = redJ[off] * rsqrtf(ssqe * invD + EPSV);
        float mx = sce;
        float scS[NBLK - 1];
        #pragma unroll
        for (int s = 0; s < NBLK - 1; ++s) {
            if (s < m) {
                scS[s] = redJ[off + 1 + s] * rsqrtf(redJ[SSQS[s]] * invD + EPSV);
                mx = fmaxf(mx, scS[s]);
            }
        }
        float scp = 0.f;
        if (i > 0) {
            scp = redJ[off + m + 1] * rsqrtf(redJ[off + m + 2] * invD + EPSV);
            mx = fmaxf(mx, scp);
        }
        float ee = __expf(sce - mx), den = ee;
        float es[NBLK - 1];
        #pragma unroll
        for (int s = 0; s < NBLK - 1; ++s) {
            es[s] = (s < m) ? __expf(scS[s] - mx) : 0.f;
            den += es[s];
        }
        float ep = 0.f;
        if (i > 0) { ep = __expf(scp - mx); den += ep; }
        const float inv = 1.f / den;
        ab[l][0] = ee * inv;
        #pragma unroll
        for (int s = 0; s < NBLK - 1; ++s)
            if (s < m) ab[l][1 + s] = es[s] * inv;
        if (i > 0) ab[l][1 + m] = ep * inv;
    }
    __syncthreads();   // barrier 3: alphas ready

    // ========== PHASE 3: emit outputs (no sync, pure FMA, no part rebuild) ==
    #pragma unroll
    for (int l = 1; l < LAYERS; ++l) {
        const int m = l / 3;
        const int i = l - 3 * m;

        float h[EPT];
        {
            const float a0 = ab[l][0];
            #pragma unroll
            for (int j = 0; j < EPT; ++j) h[j] = a0 * e[j];
        }
        #pragma unroll
        for (int s = 0; s < NBLK - 1; ++s) {
            if (s < m) {
                const float a = ab[l][1 + s];
                h[0] += a * upk(Spk[s][0],0);
                h[1] += a * upk(Spk[s][0],1);
                h[2] += a * upk(Spk[s][1],0);
                h[3] += a * upk(Spk[s][1],1);
            }
        }
        if (i > 0) {
            const float a = ab[l][1 + m];
            const int si = 2 * m + (i - 1);
            h[0] += a * upk(pp[si][0],0);
            h[1] += a * upk(pp[si][0],1);
            h[2] += a * upk(pp[si][1],0);
            h[3] += a * upk(pp[si][1],1);
        }

        {
            vf4 w0; w0.x=h[0]; w0.y=h[1]; w0.z=h[2]; w0.w=h[3];
            *reinterpret_cast<vf4*>(out + ((size_t)l * bt_total + bt) * DIM + c0) = w0;
        }
    }
}

extern "C" void kernel_launch(void* const* d_in, const int* in_sizes, int n_in,
                              void* d_out, int out_size, void* d_ws, size_t ws_size,
                              hipStream_t stream) {
    const float* lo  = (const float*)d_in[0];  // layer_outputs (L,B,T,D)
    const float* emb = (const float*)d_in[1];  // embedding (B,T,D)
    const float* qry = (const float*)d_in[2];  // queries (L,D)
    const float* wgt = (const float*)d_in[3];  // key_norm_weight (D)
    float* outp = (float*)d_out;

    const int bt_total = in_sizes[1] / DIM;    // B*T
    const int nq = in_sizes[2];                // L*D

    if (ws_size >= (size_t)nq * sizeof(float)) {
        float* qwbuf = (float*)d_ws;
        prep_qw_kernel<<<(nq + 255) / 256, 256, 0, stream>>>(qry, wgt, qwbuf, nq);
        block_attn_res_kernel<true><<<bt_total, TPB, 0, stream>>>(
            lo, emb, qwbuf, nullptr, outp, bt_total);
    } else {
        block_attn_res_kernel<false><<<bt_total, TPB, 0, stream>>>(
            lo, emb, qry, wgt, outp, bt_total);
    }
}

// Round 12
// 179.072 us; speedup vs baseline: 1.2258x; 1.0923x over previous
//
#include <hip/hip_runtime.h>
#include <hip/hip_bf16.h>

constexpr int LAYERS = 24;
constexpr int DIM    = 2048;
constexpr int NBLK   = 8;
constexpr float EPSV = 1e-6f;
constexpr int TPB    = 512;
constexpr int EPT    = 4;            // one float4 slice per thread
constexpr int NSLOT  = 147;          // total block-wide reduced scalars
constexpr int ASLOT  = 49;           // slots 0..48 belong to layers 0..11 (batch A)
constexpr int RSTR   = NSLOT + 2;    // odd stride

typedef float vf4 __attribute__((ext_vector_type(4)));

// Reduced-value layout (slot indices):
//   slot 0: ssq(emb)
//   layer l (1..23), m=l/3, i=l%3, off=OFF_TAB[l]:
//     off+0        : dot(emb, qw_l)
//     off+1+s      : dot(S_s, qw_l)          s = 0..m-1
//     i>0:  off+m+1: dot(part_l, qw_l),  off+m+2: ssq(part_l)
//     i==0: off+m+1: ssq(S_{m-1})  (computed from f32 part before overwrite)
__device__ constexpr int OFF_TAB[24] =
    {0,1,4,7,10,14,18,22,27,32,37,43,49,55,62,69,76,84,92,100,109,118,127,137};
__device__ constexpr int SSQS[7] = {9,21,36,54,75,99,126};  // ssq(S_s) slots

__device__ __forceinline__ unsigned pk2(float a, float b) {
    __hip_bfloat162 h2(__float2bfloat16(a), __float2bfloat16(b));
    union { __hip_bfloat162 h; unsigned u; } c; c.h = h2; return c.u;
}
__device__ __forceinline__ float upk(unsigned p, int hi) {
    union { unsigned u; float f; } c;
    c.u = hi ? (p & 0xffff0000u) : (p << 16);
    return c.f;
}

// DPP tree-sum over each 16-lane group (pure VALU, no DS pipe).
template<int CTRL>
__device__ __forceinline__ float dpp_add(float x) {
    int y = __builtin_amdgcn_update_dpp(0, __float_as_int(x), CTRL, 0xF, 0xF, true);
    return x + __int_as_float(y);
}
__device__ __forceinline__ float grp16_sum(float x) {
    x = dpp_add<0xB1>(x);    // + lane^1   (quad_perm[1,0,3,2])
    x = dpp_add<0x4E>(x);    // + lane^2   (quad_perm[2,3,0,1])
    x = dpp_add<0x141>(x);   // row_half_mirror
    x = dpp_add<0x140>(x);   // row_mirror
    return x;                // all 16 lanes hold the group sum
}

__global__ void prep_qw_kernel(const float* __restrict__ q,
                               const float* __restrict__ w,
                               float* __restrict__ qw, int n) {
    int idx = blockIdx.x * blockDim.x + threadIdx.x;
    if (idx < n) qw[idx] = q[idx] * w[idx & (DIM - 1)];
}

template<bool PREMUL>
__global__ void __launch_bounds__(TPB, 4)   // cap 128 unified regs; demand ~100
block_attn_res_kernel(const float* __restrict__ lo,   // (L, B*T, D)
                      const float* __restrict__ emb,  // (B*T, D)
                      const float* __restrict__ q1,   // premultiplied q*w (L,D) or raw q
                      const float* __restrict__ wgt,  // (D) -- only if !PREMUL
                      float* __restrict__ out,        // (L, B*T, D)
                      int bt_total)
{
    const int bt   = blockIdx.x;
    const int tid  = threadIdx.x;
    const int lane = tid & 63;
    const int wid  = tid >> 6;
    const int grp  = (wid << 2) | (lane >> 4);   // 16-lane group id, 0..31
    const int c0   = tid * 4;                    // thread owns d-indices [4t,4t+4)

    __shared__ float red[32][RSTR];        // group partials
    __shared__ float redJ[NSLOT + 1];      // joined scalars
    __shared__ float ab[LAYERS][12];       // normalized alphas per layer

    const float invD = 1.f / (float)DIM;
    const size_t lstride = (size_t)bt_total * DIM;
    const float* lop = lo + (size_t)bt * DIM + c0;

    // 16-lane DPP tree sum; group leader writes LDS
    auto wred = [&](float x, int slot) {
        x = grp16_sum(x);
        if ((lane & 15) == 0) red[grp][slot] = x;
    };

    // weight slice (only needed when !PREMUL)
    float wv[EPT];
    if (!PREMUL) {
        vf4 w0 = *reinterpret_cast<const vf4*>(wgt + c0);
        wv[0]=w0.x; wv[1]=w0.y; wv[2]=w0.z; wv[3]=w0.w;
    }

    // ---- embedding slice
    float e[EPT];
    {
        vf4 v0 = __builtin_nontemporal_load(
            reinterpret_cast<const vf4*>(emb + (size_t)bt * DIM + c0));
        e[0]=v0.x; e[1]=v0.y; e[2]=v0.z; e[3]=v0.w;
    }

    unsigned pp[16][EPT/2];       // part snapshots at the 16 i>0 layers, bf16x2
    unsigned Spk[NBLK-1][EPT/2];  // finished block sums S_0..S_6, bf16x2
    float part[EPT];              // running within-block partial (f32)

    // output emission for one layer (l compile-time under unroll)
    auto emit = [&](int l) {
        const int m = l / 3;
        const int i = l - 3 * m;
        float h[EPT];
        {
            const float a0 = ab[l][0];
            #pragma unroll
            for (int j = 0; j < EPT; ++j) h[j] = a0 * e[j];
        }
        #pragma unroll
        for (int s = 0; s < NBLK - 1; ++s) {
            if (s < m) {
                const float a = ab[l][1 + s];
                h[0] += a * upk(Spk[s][0],0);
                h[1] += a * upk(Spk[s][0],1);
                h[2] += a * upk(Spk[s][1],0);
                h[3] += a * upk(Spk[s][1],1);
            }
        }
        if (i > 0) {
            const float a = ab[l][1 + m];
            const int si = 2 * m + (i - 1);
            h[0] += a * upk(pp[si][0],0);
            h[1] += a * upk(pp[si][0],1);
            h[2] += a * upk(pp[si][1],0);
            h[3] += a * upk(pp[si][1],1);
        }
        vf4 w0; w0.x=h[0]; w0.y=h[1]; w0.z=h[2]; w0.w=h[3];
        *reinterpret_cast<vf4*>(out + ((size_t)l * bt_total + bt) * DIM + c0) = w0;
    };

    // per-layer phase-1 body (prefetch + dots + state evolution)
    float fb[4][EPT], qb[2][EPT];
    auto p1_body = [&](int l) {
        const int m   = l / 3;
        const int i   = l - 3 * m;
        const int off = OFF_TAB[l];
        const int pf  = l & 3;
        const int pq  = l & 1;

        float qwv[EPT];
        #pragma unroll
        for (int j = 0; j < EPT; ++j)
            qwv[j] = PREMUL ? qb[pq][j] : qb[pq][j] * wv[j];
        float fC[EPT];
        if (l < LAYERS - 1) {
            #pragma unroll
            for (int j = 0; j < EPT; ++j) fC[j] = fb[pf][j];
        }

        if (l + 4 <= LAYERS - 2) {
            vf4 u0 = __builtin_nontemporal_load(
                reinterpret_cast<const vf4*>(lop + (size_t)(l + 4) * lstride));
            fb[pf][0]=u0.x; fb[pf][1]=u0.y; fb[pf][2]=u0.z; fb[pf][3]=u0.w;
        }
        if (l + 2 <= LAYERS - 1) {
            vf4 v0 = *reinterpret_cast<const vf4*>(q1 + (size_t)(l + 2) * DIM + c0);
            qb[pq][0]=v0.x; qb[pq][1]=v0.y; qb[pq][2]=v0.z; qb[pq][3]=v0.w;
        }

        // dot(emb, qw)
        {
            float dv = e[0]*qwv[0] + e[1]*qwv[1] + e[2]*qwv[2] + e[3]*qwv[3];
            wred(dv, off);
        }
        // dot(S_s, qw); at i==0 the newest S (s=m-1) is still in f32 `part`
        #pragma unroll
        for (int s = 0; s < NBLK - 1; ++s) {
            if (s < m) {
                float dv;
                if (s == m - 1 && i == 0) {
                    dv = part[0]*qwv[0] + part[1]*qwv[1]
                       + part[2]*qwv[2] + part[3]*qwv[3];
                } else {
                    dv = upk(Spk[s][0],0)*qwv[0] + upk(Spk[s][0],1)*qwv[1]
                       + upk(Spk[s][1],0)*qwv[2] + upk(Spk[s][1],1)*qwv[3];
                }
                wred(dv, off + 1 + s);
            }
        }
        if (i > 0) {
            float dv = part[0]*qwv[0] + part[1]*qwv[1]
                     + part[2]*qwv[2] + part[3]*qwv[3];
            float sq = part[0]*part[0] + part[1]*part[1]
                     + part[2]*part[2] + part[3]*part[3];
            wred(dv, off + m + 1);
            wred(sq, off + m + 2);
            const int si = 2 * m + (i - 1);
            pp[si][0] = pk2(part[0], part[1]);
            pp[si][1] = pk2(part[2], part[3]);
        } else {
            float sq = part[0]*part[0] + part[1]*part[1]
                     + part[2]*part[2] + part[3]*part[3];
            wred(sq, off + m + 1);
        }

        if (l < LAYERS - 1) {
            if (i == 0) {
                #pragma unroll
                for (int j = 0; j < EPT; ++j) part[j] = fC[j];
            } else {
                #pragma unroll
                for (int j = 0; j < EPT; ++j) part[j] += fC[j];
            }
            if (i == 2 && m < NBLK - 1) {
                Spk[m][0] = pk2(part[0], part[1]);
                Spk[m][1] = pk2(part[2], part[3]);
            }
        }
    };

    // softmax for one layer (l = tid), writes ab[l]
    auto softmax_l = [&](int l) {
        const int m = l / 3;
        const int i = l - 3 * m;
        const int off = OFF_TAB[l];
        const float ssqe = redJ[0];
        float sce = redJ[off] * rsqrtf(ssqe * invD + EPSV);
        float mx = sce;
        float scS[NBLK - 1];
        #pragma unroll
        for (int s = 0; s < NBLK - 1; ++s) {
            if (s < m) {
                scS[s] = redJ[off + 1 + s] * rsqrtf(redJ[SSQS[s]] * invD + EPSV);
                mx = fmaxf(mx, scS[s]);
            }
        }
        float scp = 0.f;
        if (i > 0) {
            scp = redJ[off + m + 1] * rsqrtf(redJ[off + m + 2] * invD + EPSV);
            mx = fmaxf(mx, scp);
        }
        float ee = __expf(sce - mx), den = ee;
        float es[NBLK - 1];
        #pragma unroll
        for (int s = 0; s < NBLK - 1; ++s) {
            es[s] = (s < m) ? __expf(scS[s] - mx) : 0.f;
            den += es[s];
        }
        float ep = 0.f;
        if (i > 0) { ep = __expf(scp - mx); den += ep; }
        const float inv = 1.f / den;
        ab[l][0] = ee * inv;
        #pragma unroll
        for (int s = 0; s < NBLK - 1; ++s)
            if (s < m) ab[l][1 + s] = es[s] * inv;
        if (i > 0) ab[l][1 + m] = ep * inv;
    };

    // ========== PHASE 1-A: layers 0..11 ==========
    {
        vf4 u0 = __builtin_nontemporal_load(reinterpret_cast<const vf4*>(lop));
        part[0]=u0.x; part[1]=u0.y; part[2]=u0.z; part[3]=u0.w;

        vf4 w0; w0.x=e[0]; w0.y=e[1]; w0.z=e[2]; w0.w=e[3];
        *reinterpret_cast<vf4*>(out + (size_t)bt * DIM + c0) = w0;

        float sq = e[0]*e[0] + e[1]*e[1] + e[2]*e[2] + e[3]*e[3];
        wred(sq, 0);
    }
    {   // prefetch init: f layers 1..4, q layers 1..2
        #pragma unroll
        for (int k = 1; k <= 4; ++k) {
            vf4 u = __builtin_nontemporal_load(
                reinterpret_cast<const vf4*>(lop + (size_t)k * lstride));
            fb[k & 3][0]=u.x; fb[k & 3][1]=u.y; fb[k & 3][2]=u.z; fb[k & 3][3]=u.w;
        }
        vf4 q;
        q = *reinterpret_cast<const vf4*>(q1 + (size_t)1 * DIM + c0);
        qb[1][0]=q.x; qb[1][1]=q.y; qb[1][2]=q.z; qb[1][3]=q.w;
        q = *reinterpret_cast<const vf4*>(q1 + (size_t)2 * DIM + c0);
        qb[0][0]=q.x; qb[0][1]=q.y; qb[0][2]=q.z; qb[0][3]=q.w;
    }
    #pragma unroll
    for (int l = 1; l <= 11; ++l) p1_body(l);

    __syncthreads();                       // bar1: A partials in red
    if (tid < ASLOT) {
        float s = 0.f;
        #pragma unroll
        for (int g = 0; g < 32; ++g) s += red[g][tid];
        redJ[tid] = s;
    }
    __syncthreads();                       // bar2: A joined
    if (tid >= 1 && tid <= 11) softmax_l(tid);
    __syncthreads();                       // bar3: A alphas ready

    // ========== PHASE 1-B (layers 12..23) + emit A outputs (1..11) ==========
    #pragma unroll
    for (int l = 12; l < LAYERS; ++l) {
        p1_body(l);
        if (l <= 22) emit(l - 11);         // A stores overlap B loads
    }

    __syncthreads();                       // bar4: B partials in red
    if (tid < NSLOT - ASLOT) {
        const int slot = ASLOT + tid;
        float s = 0.f;
        #pragma unroll
        for (int g = 0; g < 32; ++g) s += red[g][slot];
        redJ[slot] = s;
    }
    __syncthreads();                       // bar5: B joined
    if (tid >= 12 && tid < LAYERS) softmax_l(tid);
    __syncthreads();                       // bar6: B alphas ready

    // ========== PHASE 3-B: emit outputs 12..23 ==========
    #pragma unroll
    for (int l = 12; l < LAYERS; ++l) emit(l);
}

extern "C" void kernel_launch(void* const* d_in, const int* in_sizes, int n_in,
                              void* d_out, int out_size, void* d_ws, size_t ws_size,
                              hipStream_t stream) {
    const float* lo  = (const float*)d_in[0];  // layer_outputs (L,B,T,D)
    const float* emb = (const float*)d_in[1];  // embedding (B,T,D)
    const float* qry = (const float*)d_in[2];  // queries (L,D)
    const float* wgt = (const float*)d_in[3];  // key_norm_weight (D)
    float* outp = (float*)d_out;

    const int bt_total = in_sizes[1] / DIM;    // B*T
    const int nq = in_sizes[2];                // L*D

    if (ws_size >= (size_t)nq * sizeof(float)) {
        float* qwbuf = (float*)d_ws;
        prep_qw_kernel<<<(nq + 255) / 256, 256, 0, stream>>>(qry, wgt, qwbuf, nq);
        block_attn_res_kernel<true><<<bt_total, TPB, 0, stream>>>(
            lo, emb, qwbuf, nullptr, outp, bt_total);
    } else {
        block_attn_res_kernel<false><<<bt_total, TPB, 0, stream>>>(
            lo, emb, qry, wgt, outp, bt_total);
    }
}